// Round 2
// baseline (57.114 us; speedup 1.0000x reference)
//
#include <hip/hip_runtime.h>
#include <float.h>
#include <limits.h>

#define WAVE 64

__device__ __forceinline__ void amax_upd(float v, int i, float& bv, int& bi) {
    if (v > bv || (v == bv && i < bi)) { bv = v; bi = i; }
}

// Block-wide argmax with first-index tie-break; result valid on thread 0.
template <int BLOCK>
__device__ __forceinline__ void block_argmax(float& bv, int& bi) {
#pragma unroll
    for (int off = 32; off > 0; off >>= 1) {
        float ov = __shfl_down(bv, off);
        int   oi = __shfl_down(bi, off);
        amax_upd(ov, oi, bv, bi);
    }
    __shared__ float sv[BLOCK / WAVE];
    __shared__ int   si[BLOCK / WAVE];
    int wid  = threadIdx.x / WAVE;
    int lane = threadIdx.x % WAVE;
    if (lane == 0) { sv[wid] = bv; si[wid] = bi; }
    __syncthreads();
    if (threadIdx.x == 0) {
        for (int w = 1; w < BLOCK / WAVE; ++w) amax_upd(sv[w], si[w], bv, bi);
    }
}

// Normalize is_greedy (bool-byte OR int32 layout) into int flags in ws.
// Reading min(B,16) words = 64 bytes is in-bounds under both layouts (B=64).
__global__ void k_decode_greedy(const void* __restrict__ isg_raw,
                                int* __restrict__ g_out, int B) {
    __shared__ int s_is_int;
    if (threadIdx.x == 0) {
        const unsigned* w = (const unsigned*)isg_raw;
        int nw = B < 16 ? B : 16;
        int is_int = 1;
        for (int i = 0; i < nw; ++i) if (w[i] > 1u) { is_int = 0; break; }
        s_is_int = is_int;
    }
    __syncthreads();
    for (int b = threadIdx.x; b < B; b += blockDim.x) {
        int v = s_is_int ? ((const int*)isg_raw)[b]
                         : (int)((const unsigned char*)isg_raw)[b];
        g_out[b] = v ? 1 : 0;
    }
}

// One block per token row i; computes argmax(target_probs[i,:]) only if the
// owning request is greedy.
__global__ void __launch_bounds__(256) k_target_argmax(
    const float* __restrict__ tp, const int* __restrict__ cu,
    const int* __restrict__ g_flags,
    int* __restrict__ ws_am, int B, int V, int N)
{
    int i = blockIdx.x;
    if (i >= N) return;
    // req id = searchsorted(cu, i, side='right') = count of cu[b] <= i
    int b = 0;
    while (b < B && cu[b] <= i) ++b;
    if (b >= B || !g_flags[b]) return;

    const float* row = tp + (size_t)i * V;
    float bv = -FLT_MAX; int bi = INT_MAX;
    int V4 = V >> 2;
    const float4* row4 = (const float4*)row;
    for (int p = threadIdx.x; p < V4; p += blockDim.x) {
        float4 x = row4[p];
        int base = p << 2;
        amax_upd(x.x, base,     bv, bi);
        amax_upd(x.y, base + 1, bv, bi);
        amax_upd(x.z, base + 2, bv, bi);
        amax_upd(x.w, base + 3, bv, bi);
    }
    for (int v = (V4 << 2) + threadIdx.x; v < V; v += blockDim.x)
        amax_upd(row[v], v, bv, bi);
    block_argmax<256>(bv, bi);
    if (threadIdx.x == 0) ws_am[i] = bi;
}

// One block per request.
__global__ void __launch_bounds__(256) k_finalize(
    const int* __restrict__ out_init,
    const int* __restrict__ cu,
    const int* __restrict__ draft_tok_ids,
    const float* __restrict__ dp_all,
    const float* __restrict__ tp_all,
    const int* __restrict__ bonus,
    const float* __restrict__ uni,
    const float* __restrict__ q,
    const int* __restrict__ g_flags,
    const int* __restrict__ ws_am,
    int* __restrict__ out,
    int B, int Sl, int V, int N)
{
    int b = blockIdx.x;
    int tid = threadIdx.x;
    int cu_b  = cu[b];
    int start = (b == 0) ? 0 : cu[b - 1];
    int n_per = cu_b - start;
    bool greedy = g_flags[b] != 0;

    __shared__ int s_out[64];     // Sl+1 <= 64
    __shared__ int s_rec_tok;     // global token idx needing recovery, or -1
    __shared__ int s_rec_pos;

    for (int j = tid; j <= Sl; j += blockDim.x)
        s_out[j] = out_init[b * (Sl + 1) + j];
    if (tid == 0) { s_rec_tok = -1; s_rec_pos = -1; }
    __syncthreads();

    if (tid == 0) {
        int lim = min(n_per, Sl);
        if (greedy) {
            int first_mm = n_per;
            for (int pos = 0; pos < lim; ++pos) {
                int g = min(max(start + pos, 0), N - 1);
                if (draft_tok_ids[g] != ws_am[g]) { first_mm = pos; break; }
            }
            int copy_len = min(first_mm + 1, n_per);
            for (int j = 0; j < copy_len && j <= Sl; ++j) {
                int g = min(max(start + j, 0), N - 1);
                s_out[j] = ws_am[g];
            }
            if (first_mm >= n_per && n_per <= Sl) s_out[n_per] = bonus[b];
        } else {
            int first_rej = Sl;   // default when no rejection among valid
            for (int pos = 0; pos < lim; ++pos) {
                int g = min(max(start + pos, 0), N - 1);
                int t = draft_tok_ids[g];
                float dpv = dp_all[(size_t)g * V + t];
                float tpv = tp_all[(size_t)g * V + t];
                float uv  = uni[g];
                bool acc = (dpv > 0.0f) && (tpv / dpv >= uv);
                if (!acc) { first_rej = pos; break; }
            }
            int acc_len = min(first_rej, min(n_per, Sl));
            for (int pos = 0; pos < acc_len; ++pos) {
                int g = min(max(start + pos, 0), N - 1);
                s_out[pos] = draft_tok_ids[g];
            }
            if (first_rej < min(n_per, Sl)) {
                s_rec_tok = min(max(start + first_rej, 0), N - 1);
                s_rec_pos = first_rej;
            }
            if (first_rej >= n_per && n_per <= Sl) s_out[n_per] = bonus[b];
        }
    }
    __syncthreads();

    int rt = s_rec_tok;           // uniform across block
    if (rt >= 0) {
        const float* tprow = tp_all + (size_t)rt * V;
        const float* dprow = dp_all + (size_t)rt * V;
        const float* qrow  = q + (size_t)b * V;
        float bv = -FLT_MAX; int bi = INT_MAX;
        int V4 = V >> 2;
        const float4* t4 = (const float4*)tprow;
        const float4* d4 = (const float4*)dprow;
        const float4* q4 = (const float4*)qrow;
        for (int p = tid; p < V4; p += blockDim.x) {
            float4 tv = t4[p], dv = d4[p], qv = q4[p];
            int base = p << 2;
            amax_upd(fmaxf(tv.x - dv.x, 0.0f) / qv.x, base,     bv, bi);
            amax_upd(fmaxf(tv.y - dv.y, 0.0f) / qv.y, base + 1, bv, bi);
            amax_upd(fmaxf(tv.z - dv.z, 0.0f) / qv.z, base + 2, bv, bi);
            amax_upd(fmaxf(tv.w - dv.w, 0.0f) / qv.w, base + 3, bv, bi);
        }
        for (int v = (V4 << 2) + tid; v < V; v += blockDim.x)
            amax_upd(fmaxf(tprow[v] - dprow[v], 0.0f) / qrow[v], v, bv, bi);
        block_argmax<256>(bv, bi);
        if (tid == 0) s_out[s_rec_pos] = bi;
    }
    __syncthreads();

    for (int j = tid; j <= Sl; j += blockDim.x)
        out[b * (Sl + 1) + j] = s_out[j];
}

extern "C" void kernel_launch(void* const* d_in, const int* in_sizes, int n_in,
                              void* d_out, int out_size, void* d_ws, size_t ws_size,
                              hipStream_t stream) {
    const int*   out_init  = (const int*)d_in[0];
    const int*   cu        = (const int*)d_in[1];
    const int*   draft_tok = (const int*)d_in[2];
    const float* dp        = (const float*)d_in[3];
    const float* tp        = (const float*)d_in[4];
    const int*   bonus     = (const int*)d_in[5];
    const float* uni       = (const float*)d_in[6];
    const float* q         = (const float*)d_in[7];
    const void*  isg_raw   = (const void*)d_in[8];
    int* out = (int*)d_out;

    int B   = in_sizes[5];          // bonus_token_ids: (B,)
    int Sp1 = out_size / B;         // S+1
    int Sl  = Sp1 - 1;
    int N   = in_sizes[2];          // draft_token_ids: (N,)
    int V   = in_sizes[3] / N;      // draft_probs: (N,V)
    int* ws_am    = (int*)d_ws;     // N ints
    int* ws_gflag = ws_am + N;      // B ints

    k_decode_greedy<<<1, 64, 0, stream>>>(isg_raw, ws_gflag, B);
    k_target_argmax<<<N, 256, 0, stream>>>(tp, cu, ws_gflag, ws_am, B, V, N);
    k_finalize<<<B, 256, 0, stream>>>(out_init, cu, draft_tok, dp, tp, bonus,
                                      uni, q, ws_gflag, ws_am, out, B, Sl, V, N);
}

// Round 3
// 39.389 us; speedup vs baseline: 1.4500x; 1.4500x over previous
//
#include <hip/hip_runtime.h>
#include <float.h>
#include <limits.h>

#define WAVE 64
#define RCHUNKS 4

__device__ __forceinline__ void amax_upd(float v, int i, float& bv, int& bi) {
    if (v > bv || (v == bv && i < bi)) { bv = v; bi = i; }
}

// Block-wide argmax with first-index tie-break; result valid on thread 0.
template <int BLOCK>
__device__ __forceinline__ void block_argmax(float& bv, int& bi) {
#pragma unroll
    for (int off = 32; off > 0; off >>= 1) {
        float ov = __shfl_down(bv, off);
        int   oi = __shfl_down(bi, off);
        amax_upd(ov, oi, bv, bi);
    }
    __shared__ float sv[BLOCK / WAVE];
    __shared__ int   si[BLOCK / WAVE];
    int wid  = threadIdx.x / WAVE;
    int lane = threadIdx.x % WAVE;
    if (lane == 0) { sv[wid] = bv; si[wid] = bi; }
    __syncthreads();
    if (threadIdx.x == 0) {
        for (int w = 1; w < BLOCK / WAVE; ++w) amax_upd(sv[w], si[w], bv, bi);
    }
}

// is_greedy may be byte-packed bools or int32; detect from first
// min(B,16) words (64 bytes, in-bounds under both layouts).
__device__ __forceinline__ bool get_greedy(const void* isg_raw, int B, int b) {
    const unsigned* w = (const unsigned*)isg_raw;
    int nw = B < 16 ? B : 16;
    bool is_int = true;
    for (int i = 0; i < nw; ++i) if (w[i] > 1u) { is_int = false; break; }
    int v = is_int ? ((const int*)isg_raw)[b]
                   : (int)((const unsigned char*)isg_raw)[b];
    return v != 0;
}

// K1: one block per token row. Greedy rows: full argmax -> ws_am[i].
// Non-greedy rows: scalar accept flag -> ws_acc[i].
__global__ void __launch_bounds__(1024) k_rows(
    const float* __restrict__ tp, const float* __restrict__ dp,
    const int* __restrict__ cu, const void* __restrict__ isg_raw,
    const int* __restrict__ draft_tok, const float* __restrict__ uni,
    int* __restrict__ ws_am, int* __restrict__ ws_acc,
    int B, int V, int N)
{
    int i = blockIdx.x;
    int b = 0;
    while (b < B && cu[b] <= i) ++b;
    if (b >= B) return;
    if (!get_greedy(isg_raw, B, b)) {
        if (threadIdx.x == 0) {
            int t = draft_tok[i];
            float dpv = dp[(size_t)i * V + t];
            float tpv = tp[(size_t)i * V + t];
            float uv  = uni[i];
            ws_acc[i] = ((dpv > 0.0f) && (tpv / dpv >= uv)) ? 1 : 0;
        }
        return;
    }
    const float* row = tp + (size_t)i * V;
    float bv = -FLT_MAX; int bi = INT_MAX;
    int V4 = V >> 2;
    const float4* row4 = (const float4*)row;
    for (int p = threadIdx.x; p < V4; p += blockDim.x) {
        float4 x = row4[p];
        int base = p << 2;
        amax_upd(x.x, base,     bv, bi);
        amax_upd(x.y, base + 1, bv, bi);
        amax_upd(x.z, base + 2, bv, bi);
        amax_upd(x.w, base + 3, bv, bi);
    }
    for (int v = (V4 << 2) + threadIdx.x; v < V; v += blockDim.x)
        amax_upd(row[v], v, bv, bi);
    block_argmax<1024>(bv, bi);
    if (threadIdx.x == 0) ws_am[i] = bi;
}

// K2: RCHUNKS blocks per request; partial argmax of max(tp-dp,0)/q over a
// contiguous V-chunk of the first-rejected row (non-greedy only).
__global__ void __launch_bounds__(512) k_recover(
    const float* __restrict__ tp, const float* __restrict__ dp,
    const float* __restrict__ q, const int* __restrict__ cu,
    const void* __restrict__ isg_raw, const int* __restrict__ ws_acc,
    float* __restrict__ ws_pval, int* __restrict__ ws_pidx,
    int B, int Sl, int V, int N)
{
    int b = blockIdx.x / RCHUNKS;
    int c = blockIdx.x % RCHUNKS;
    if (get_greedy(isg_raw, B, b)) return;
    int cu_b  = cu[b];
    int start = (b == 0) ? 0 : cu[b - 1];
    int n_per = cu_b - start;
    int lim = min(n_per, Sl);
    int first_rej = Sl;
    for (int pos = 0; pos < lim; ++pos) {
        int g = min(max(start + pos, 0), N - 1);
        if (!ws_acc[g]) { first_rej = pos; break; }
    }
    if (first_rej >= lim) return;   // no recovery needed
    int g = min(max(start + first_rej, 0), N - 1);
    const float* tprow = tp + (size_t)g * V;
    const float* dprow = dp + (size_t)g * V;
    const float* qrow  = q + (size_t)b * V;

    int v0 = c * (V / RCHUNKS);
    int v1 = (c + 1 == RCHUNKS) ? V : v0 + (V / RCHUNKS);
    float bv = -FLT_MAX; int bi = INT_MAX;
    int a0 = (v0 + 3) & ~3;
    int a1 = v1 & ~3;
    for (int v = v0 + (int)threadIdx.x; v < min(a0, v1); v += blockDim.x)
        amax_upd(fmaxf(tprow[v] - dprow[v], 0.0f) / qrow[v], v, bv, bi);
    const float4* t4 = (const float4*)(tprow + a0);
    const float4* d4 = (const float4*)(dprow + a0);
    const float4* q4 = (const float4*)(qrow  + a0);
    int np = (a1 - a0) >> 2;
    for (int p = threadIdx.x; p < np; p += blockDim.x) {
        float4 tv = t4[p], dv = d4[p], qv = q4[p];
        int base = a0 + (p << 2);
        amax_upd(fmaxf(tv.x - dv.x, 0.0f) / qv.x, base,     bv, bi);
        amax_upd(fmaxf(tv.y - dv.y, 0.0f) / qv.y, base + 1, bv, bi);
        amax_upd(fmaxf(tv.z - dv.z, 0.0f) / qv.z, base + 2, bv, bi);
        amax_upd(fmaxf(tv.w - dv.w, 0.0f) / qv.w, base + 3, bv, bi);
    }
    for (int v = a1 + (int)threadIdx.x; v < v1; v += blockDim.x)
        amax_upd(fmaxf(tprow[v] - dprow[v], 0.0f) / qrow[v], v, bv, bi);
    block_argmax<512>(bv, bi);
    if (threadIdx.x == 0) {
        ws_pval[b * RCHUNKS + c] = bv;
        ws_pidx[b * RCHUNKS + c] = bi;
    }
}

// K3: per-request assembly from L2-hot flags/partials; no HBM gathers on the
// serial path.
__global__ void __launch_bounds__(64) k_assemble(
    const int* __restrict__ out_init, const int* __restrict__ cu,
    const int* __restrict__ draft_tok, const int* __restrict__ bonus,
    const void* __restrict__ isg_raw, const int* __restrict__ ws_am,
    const int* __restrict__ ws_acc, const float* __restrict__ ws_pval,
    const int* __restrict__ ws_pidx, int* __restrict__ out,
    int B, int Sl, int N)
{
    int b = blockIdx.x;
    int tid = threadIdx.x;
    int cu_b  = cu[b];
    int start = (b == 0) ? 0 : cu[b - 1];
    int n_per = cu_b - start;
    bool greedy = get_greedy(isg_raw, B, b);

    __shared__ int s_out[64];
    for (int j = tid; j <= Sl; j += blockDim.x)
        s_out[j] = out_init[b * (Sl + 1) + j];
    __syncthreads();

    if (tid == 0) {
        int lim = min(n_per, Sl);
        if (greedy) {
            int first_mm = n_per;
            for (int pos = 0; pos < lim; ++pos) {
                int g = min(max(start + pos, 0), N - 1);
                if (draft_tok[g] != ws_am[g]) { first_mm = pos; break; }
            }
            int copy_len = min(first_mm + 1, n_per);
            for (int j = 0; j < copy_len && j <= Sl; ++j) {
                int g = min(max(start + j, 0), N - 1);
                s_out[j] = ws_am[g];
            }
            if (first_mm >= n_per && n_per <= Sl) s_out[n_per] = bonus[b];
        } else {
            int first_rej = Sl;
            for (int pos = 0; pos < lim; ++pos) {
                int g = min(max(start + pos, 0), N - 1);
                if (!ws_acc[g]) { first_rej = pos; break; }
            }
            int acc_len = min(first_rej, lim);
            for (int pos = 0; pos < acc_len; ++pos) {
                int g = min(max(start + pos, 0), N - 1);
                s_out[pos] = draft_tok[g];
            }
            if (first_rej < lim) {
                float bv = -FLT_MAX; int bi = INT_MAX;
                for (int c = 0; c < RCHUNKS; ++c)
                    amax_upd(ws_pval[b * RCHUNKS + c],
                             ws_pidx[b * RCHUNKS + c], bv, bi);
                s_out[first_rej] = bi;
            }
            if (first_rej >= n_per && n_per <= Sl) s_out[n_per] = bonus[b];
        }
    }
    __syncthreads();

    for (int j = tid; j <= Sl; j += blockDim.x)
        out[b * (Sl + 1) + j] = s_out[j];
}

extern "C" void kernel_launch(void* const* d_in, const int* in_sizes, int n_in,
                              void* d_out, int out_size, void* d_ws, size_t ws_size,
                              hipStream_t stream) {
    const int*   out_init  = (const int*)d_in[0];
    const int*   cu        = (const int*)d_in[1];
    const int*   draft_tok = (const int*)d_in[2];
    const float* dp        = (const float*)d_in[3];
    const float* tp        = (const float*)d_in[4];
    const int*   bonus     = (const int*)d_in[5];
    const float* uni       = (const float*)d_in[6];
    const float* q         = (const float*)d_in[7];
    const void*  isg_raw   = (const void*)d_in[8];
    int* out = (int*)d_out;

    int B   = in_sizes[5];          // bonus_token_ids: (B,)
    int Sp1 = out_size / B;         // S+1
    int Sl  = Sp1 - 1;
    int N   = in_sizes[2];          // draft_token_ids: (N,)
    int V   = in_sizes[3] / N;      // draft_probs: (N,V)

    int*   ws_am   = (int*)d_ws;            // N ints
    int*   ws_acc  = ws_am + N;             // N ints
    float* ws_pval = (float*)(ws_acc + N);  // B*RCHUNKS floats
    int*   ws_pidx = (int*)(ws_pval + B * RCHUNKS); // B*RCHUNKS ints

    k_rows<<<N, 1024, 0, stream>>>(tp, dp, cu, isg_raw, draft_tok, uni,
                                   ws_am, ws_acc, B, V, N);
    k_recover<<<B * RCHUNKS, 512, 0, stream>>>(tp, dp, q, cu, isg_raw, ws_acc,
                                               ws_pval, ws_pidx, B, Sl, V, N);
    k_assemble<<<B, 64, 0, stream>>>(out_init, cu, draft_tok, bonus, isg_raw,
                                     ws_am, ws_acc, ws_pval, ws_pidx, out,
                                     B, Sl, N);
}

// Round 4
// 24.950 us; speedup vs baseline: 2.2891x; 1.5787x over previous
//
#include <hip/hip_runtime.h>
#include <float.h>
#include <limits.h>

#define WAVE 64
#define CHUNKS 8
#define MAXB 1024      // max requests supported
#define MAXW 8192      // max B*Sl work items in prep

__device__ __forceinline__ void amax_upd(float v, int i, float& bv, int& bi) {
    if (v > bv || (v == bv && i < bi)) { bv = v; bi = i; }
}

// Block-wide argmax with first-index tie-break; result valid on thread 0.
template <int BLOCK>
__device__ __forceinline__ void block_argmax(float& bv, int& bi) {
#pragma unroll
    for (int off = 32; off > 0; off >>= 1) {
        float ov = __shfl_down(bv, off);
        int   oi = __shfl_down(bi, off);
        amax_upd(ov, oi, bv, bi);
    }
    __shared__ float sv[BLOCK / WAVE];
    __shared__ int   si[BLOCK / WAVE];
    int wid  = threadIdx.x / WAVE;
    int lane = threadIdx.x % WAVE;
    if (lane == 0) { sv[wid] = bv; si[wid] = bi; }
    __syncthreads();
    if (threadIdx.x == 0) {
        for (int w = 1; w < BLOCK / WAVE; ++w) amax_upd(sv[w], si[w], bv, bi);
    }
}

// K_prep: single block. Decodes is_greedy (byte-bool or int32 layout),
// computes accept flags with fully parallel gathers, per-request first_rej,
// and builds a compacted work list of argmax jobs + per-request metadata.
// meta[b] = {greedy, first_rej, entry_base, entry_cnt}
__global__ void __launch_bounds__(1024) k_prep(
    const int* __restrict__ cu, const void* __restrict__ isg_raw,
    const int* __restrict__ draft_tok, const float* __restrict__ dp,
    const float* __restrict__ tp, const float* __restrict__ uni,
    int* __restrict__ ws_hdr, int* __restrict__ ws_meta,
    int* __restrict__ ws_rows, int* __restrict__ ws_reqs,
    int B, int Sl, int V, int N)
{
    int tid = threadIdx.x;
    __shared__ int s_isint;
    __shared__ int s_start[MAXB], s_nper[MAXB], s_greedy[MAXB];
    __shared__ int s_fr[MAXB], s_cnt[MAXB], s_base[MAXB];
    __shared__ unsigned char s_acc[MAXW];

    if (tid == 0) {
        // layout detect: first min(B,16) words (64B) in-bounds either way
        const unsigned* w = (const unsigned*)isg_raw;
        int nw = B < 16 ? B : 16;
        int is_int = 1;
        for (int i = 0; i < nw; ++i) if (w[i] > 1u) { is_int = 0; break; }
        s_isint = is_int;
    }
    __syncthreads();

    for (int b = tid; b < B; b += blockDim.x) {
        int cb = cu[b];
        int st = b ? cu[b - 1] : 0;
        s_start[b] = st;
        s_nper[b]  = cb - st;
        int v = s_isint ? ((const int*)isg_raw)[b]
                        : (int)((const unsigned char*)isg_raw)[b];
        s_greedy[b] = v ? 1 : 0;
    }
    __syncthreads();

    // accept flags — independent gathers, fully parallel
    for (int w = tid; w < B * Sl; w += blockDim.x) {
        int b = w / Sl, pos = w % Sl;
        int acc = 1;
        int lim = min(s_nper[b], Sl);
        if (!s_greedy[b] && pos < lim) {
            int g = min(max(s_start[b] + pos, 0), N - 1);
            int t = draft_tok[g];
            float dpv = dp[(size_t)g * V + t];
            float tpv = tp[(size_t)g * V + t];
            acc = ((dpv > 0.0f) && (tpv / dpv >= uni[g])) ? 1 : 0;
        }
        s_acc[w] = (unsigned char)acc;
    }
    __syncthreads();

    for (int b = tid; b < B; b += blockDim.x) {
        int lim = min(s_nper[b], Sl);
        int fr = Sl;
        for (int p = 0; p < lim; ++p)
            if (!s_acc[b * Sl + p]) { fr = p; break; }
        s_fr[b] = fr;
        s_cnt[b] = s_greedy[b] ? s_nper[b] : ((fr < lim) ? 1 : 0);
    }
    __syncthreads();

    if (tid == 0) {
        int acc = 0;
        for (int b = 0; b < B; ++b) { s_base[b] = acc; acc += s_cnt[b]; }
        ws_hdr[0] = acc;
    }
    __syncthreads();

    for (int b = tid; b < B; b += blockDim.x) {
        int base = s_base[b];
        int st = s_start[b];
        if (s_greedy[b]) {
            for (int k = 0; k < s_nper[b]; ++k) {
                ws_rows[base + k] = min(max(st + k, 0), N - 1);
                ws_reqs[base + k] = b;
            }
        } else if (s_cnt[b]) {
            ws_rows[base] = min(max(st + s_fr[b], 0), N - 1);
            ws_reqs[base] = b | (1 << 30);
        }
        ws_meta[b * 4 + 0] = s_greedy[b];
        ws_meta[b * 4 + 1] = s_fr[b];
        ws_meta[b * 4 + 2] = base;
        ws_meta[b * 4 + 3] = s_cnt[b];
    }
}

// K_argmax: block e*CHUNKS+c does chunk c of work entry e.
// greedy entry: argmax(tp[g, v0:v1]); recovery: argmax(max(tp-dp,0)/q[b]).
__global__ void __launch_bounds__(256) k_argmax(
    const float* __restrict__ tp, const float* __restrict__ dp,
    const float* __restrict__ q, const int* __restrict__ ws_hdr,
    const int* __restrict__ ws_rows, const int* __restrict__ ws_reqs,
    float* __restrict__ ws_pval, int* __restrict__ ws_pidx, int V)
{
    int e = blockIdx.x / CHUNKS;
    int c = blockIdx.x % CHUNKS;
    if (e >= ws_hdr[0]) return;
    int g  = ws_rows[e];
    int rq = ws_reqs[e];
    int b  = rq & 0x3FFFFFFF;
    int rec = (rq >> 30) & 1;

    int v0 = (int)((long long)V * c / CHUNKS);
    int v1 = (int)((long long)V * (c + 1) / CHUNKS);
    float bv = -FLT_MAX; int bi = INT_MAX;
    int a0 = (v0 + 3) & ~3;
    int a1 = v1 & ~3;

    if (!rec) {
        const float* row = tp + (size_t)g * V;
        for (int v = v0 + (int)threadIdx.x; v < min(a0, v1); v += blockDim.x)
            amax_upd(row[v], v, bv, bi);
        const float4* r4 = (const float4*)(row + a0);
        int np = (a1 - a0) >> 2;
        for (int p = threadIdx.x; p < np; p += blockDim.x) {
            float4 x = r4[p];
            int base = a0 + (p << 2);
            amax_upd(x.x, base,     bv, bi);
            amax_upd(x.y, base + 1, bv, bi);
            amax_upd(x.z, base + 2, bv, bi);
            amax_upd(x.w, base + 3, bv, bi);
        }
        for (int v = max(a1, a0) + (int)threadIdx.x; v < v1; v += blockDim.x)
            amax_upd(row[v], v, bv, bi);
    } else {
        const float* tprow = tp + (size_t)g * V;
        const float* dprow = dp + (size_t)g * V;
        const float* qrow  = q  + (size_t)b * V;
        for (int v = v0 + (int)threadIdx.x; v < min(a0, v1); v += blockDim.x)
            amax_upd(fmaxf(tprow[v] - dprow[v], 0.0f) / qrow[v], v, bv, bi);
        const float4* t4 = (const float4*)(tprow + a0);
        const float4* d4 = (const float4*)(dprow + a0);
        const float4* q4 = (const float4*)(qrow  + a0);
        int np = (a1 - a0) >> 2;
        for (int p = threadIdx.x; p < np; p += blockDim.x) {
            float4 tv = t4[p], dv = d4[p], qv = q4[p];
            int base = a0 + (p << 2);
            amax_upd(fmaxf(tv.x - dv.x, 0.0f) / qv.x, base,     bv, bi);
            amax_upd(fmaxf(tv.y - dv.y, 0.0f) / qv.y, base + 1, bv, bi);
            amax_upd(fmaxf(tv.z - dv.z, 0.0f) / qv.z, base + 2, bv, bi);
            amax_upd(fmaxf(tv.w - dv.w, 0.0f) / qv.w, base + 3, bv, bi);
        }
        for (int v = max(a1, a0) + (int)threadIdx.x; v < v1; v += blockDim.x)
            amax_upd(fmaxf(tprow[v] - dprow[v], 0.0f) / qrow[v], v, bv, bi);
    }
    block_argmax<256>(bv, bi);
    if (threadIdx.x == 0) {
        ws_pval[e * CHUNKS + c] = bv;
        ws_pidx[e * CHUNKS + c] = bi;
    }
}

// K_assemble: per request; partial-reduce + output assembly, all L2-hot.
__global__ void __launch_bounds__(64) k_assemble(
    const int* __restrict__ out_init, const int* __restrict__ cu,
    const int* __restrict__ draft_tok, const int* __restrict__ bonus,
    const int* __restrict__ ws_meta, const float* __restrict__ ws_pval,
    const int* __restrict__ ws_pidx, int* __restrict__ out,
    int B, int Sl, int N)
{
    int b = blockIdx.x;
    int tid = threadIdx.x;
    int cb = cu[b];
    int st = b ? cu[b - 1] : 0;
    int n_per = cb - st;
    int greedy = ws_meta[b * 4 + 0];
    int fr     = ws_meta[b * 4 + 1];
    int base   = ws_meta[b * 4 + 2];

    __shared__ int s_out[128];
    __shared__ int s_am[64];
    for (int j = tid; j <= Sl; j += blockDim.x)
        s_out[j] = out_init[b * (Sl + 1) + j];

    if (greedy) {
        for (int j = tid; j < n_per && j < 64; j += blockDim.x) {
            float bv = -FLT_MAX; int bi = INT_MAX;
            for (int c = 0; c < CHUNKS; ++c)
                amax_upd(ws_pval[(base + j) * CHUNKS + c],
                         ws_pidx[(base + j) * CHUNKS + c], bv, bi);
            s_am[j] = bi;
        }
    }
    __syncthreads();

    if (tid == 0) {
        int lim = min(n_per, Sl);
        if (greedy) {
            int first_mm = n_per;
            for (int pos = 0; pos < lim; ++pos) {
                int g = min(max(st + pos, 0), N - 1);
                if (draft_tok[g] != s_am[pos]) { first_mm = pos; break; }
            }
            int copy_len = min(first_mm + 1, n_per);
            for (int j = 0; j < copy_len && j <= Sl; ++j)
                s_out[j] = s_am[j];
            if (first_mm >= n_per && n_per <= Sl) s_out[n_per] = bonus[b];
        } else {
            int acc_len = min(fr, lim);
            for (int pos = 0; pos < acc_len; ++pos) {
                int g = min(max(st + pos, 0), N - 1);
                s_out[pos] = draft_tok[g];
            }
            if (fr < lim) {
                float bv = -FLT_MAX; int bi = INT_MAX;
                for (int c = 0; c < CHUNKS; ++c)
                    amax_upd(ws_pval[base * CHUNKS + c],
                             ws_pidx[base * CHUNKS + c], bv, bi);
                s_out[fr] = bi;
            }
            if (fr >= n_per && n_per <= Sl) s_out[n_per] = bonus[b];
        }
    }
    __syncthreads();

    for (int j = tid; j <= Sl; j += blockDim.x)
        out[b * (Sl + 1) + j] = s_out[j];
}

extern "C" void kernel_launch(void* const* d_in, const int* in_sizes, int n_in,
                              void* d_out, int out_size, void* d_ws, size_t ws_size,
                              hipStream_t stream) {
    const int*   out_init  = (const int*)d_in[0];
    const int*   cu        = (const int*)d_in[1];
    const int*   draft_tok = (const int*)d_in[2];
    const float* dp        = (const float*)d_in[3];
    const float* tp        = (const float*)d_in[4];
    const int*   bonus     = (const int*)d_in[5];
    const float* uni       = (const float*)d_in[6];
    const float* q         = (const float*)d_in[7];
    const void*  isg_raw   = (const void*)d_in[8];
    int* out = (int*)d_out;

    int B   = in_sizes[5];          // bonus_token_ids: (B,)
    int Sp1 = out_size / B;         // S+1
    int Sl  = Sp1 - 1;
    int N   = in_sizes[2];          // draft_token_ids: (N,)
    int V   = in_sizes[3] / N;      // draft_probs: (N,V)
    int MAXE = N + B;

    int*   ws_hdr  = (int*)d_ws;                    // 1
    int*   ws_meta = ws_hdr + 16;                   // B*4
    int*   ws_rows = ws_meta + B * 4;               // MAXE
    int*   ws_reqs = ws_rows + MAXE;                // MAXE
    float* ws_pval = (float*)(ws_reqs + MAXE);      // MAXE*CHUNKS
    int*   ws_pidx = (int*)(ws_pval + MAXE * CHUNKS); // MAXE*CHUNKS

    k_prep<<<1, 1024, 0, stream>>>(cu, isg_raw, draft_tok, dp, tp, uni,
                                   ws_hdr, ws_meta, ws_rows, ws_reqs,
                                   B, Sl, V, N);
    k_argmax<<<MAXE * CHUNKS, 256, 0, stream>>>(tp, dp, q, ws_hdr, ws_rows,
                                                ws_reqs, ws_pval, ws_pidx, V);
    k_assemble<<<B, 64, 0, stream>>>(out_init, cu, draft_tok, bonus, ws_meta,
                                     ws_pval, ws_pidx, out, B, Sl, N);
}